// Round 18
// baseline (177.097 us; speedup 1.0000x reference)
//
#include <hip/hip_runtime.h>
#include <hip/hip_bf16.h>

typedef __attribute__((ext_vector_type(8))) short bf16x8;
typedef __attribute__((ext_vector_type(4))) float f32x4;
typedef unsigned short u16;

#define NTOK 2048
#define DDIM 1024
#define HDIM 4096
#define KEXP 8

#define BM 320   // covers any realistic expert count in ONE tile (counts ~256±15)
#define BK 64
#define NDESC 16

__device__ __forceinline__ u16 f2bf(float f) {
  __hip_bfloat16 b = __float2bfloat16(f);   // RNE; pairs fuse to v_cvt_pk_bf16_f32
  union { __hip_bfloat16 b; u16 u; } c; c.b = b; return c.u;
}
__device__ __forceinline__ unsigned pk2(float a, float b) {
  return (unsigned)f2bf(a) | ((unsigned)f2bf(b) << 16);
}

// fenced raw barrier: own DS ops drained, no vmcnt drain, no code motion across
#define BAR() do { \
  asm volatile("s_waitcnt lgkmcnt(0)" ::: "memory"); \
  __builtin_amdgcn_sched_barrier(0); \
  __builtin_amdgcn_s_barrier(); \
  __builtin_amdgcn_sched_barrier(0); \
} while (0)

// ---------------- routing: counting sort + tile worklist ----------------
__global__ void route_kernel(const float* __restrict__ cw, int* __restrict__ offs,
                             int* __restrict__ perm, float* __restrict__ wsel,
                             int* __restrict__ desc) {
  __shared__ int cnt[KEXP];
  __shared__ int base[KEXP];
  const int t = threadIdx.x;  // 256 threads, 8 tokens each
  if (t < KEXP) cnt[t] = 0;
  __syncthreads();
  int eid[8]; float wv[8];
  #pragma unroll
  for (int i = 0; i < 8; i++) {
    const int tok = t * 8 + i;
    const float* p = cw + tok * KEXP;
    int best = 0; float bw = p[0];
    #pragma unroll
    for (int k = 1; k < KEXP; k++) { float v = p[k]; if (v > bw) { bw = v; best = k; } }
    eid[i] = best; wv[i] = bw;
    atomicAdd(&cnt[best], 1);
  }
  __syncthreads();
  if (t == 0) {
    int s = 0, nd = 0;
    for (int k = 0; k < KEXP; k++) {
      const int ck = cnt[k];
      base[k] = s; offs[k] = s;
      for (int m0 = 0; m0 < ck && nd < NDESC; m0 += BM)
        desc[nd++] = (k << 12) | (s + m0);   // pack expert(3b) | slot0(12b)
      s += ck;
    }
    offs[KEXP] = s;
    for (; nd < NDESC; nd++) desc[nd] = -1;
  }
  __syncthreads();
  #pragma unroll
  for (int i = 0; i < 8; i++) {
    const int tok = t * 8 + i;
    const int pos = atomicAdd(&base[eid[i]], 1);
    perm[pos] = tok;
    wsel[pos] = wv[i];
  }
}

// ---------------- gather x rows into expert-sorted bf16 ----------------
__global__ void gather_x(const float* __restrict__ x, const int* __restrict__ perm,
                         u16* __restrict__ Xb) {
  const int slot = blockIdx.x;
  const int tok = perm[slot];
  const int t = threadIdx.x;  // 256
  float4 v = ((const float4*)(x + (size_t)tok * DDIM))[t];
  ushort4 o; o.x = f2bf(v.x); o.y = f2bf(v.y); o.z = f2bf(v.z); o.w = f2bf(v.w);
  ((ushort4*)(Xb + (size_t)slot * DDIM))[t] = o;
}

// ---------------- pass 1: H = silu(X@wg) * (X@wu) ----------------
// 512 thr = 8 waves (4m x 2n), BM=320, BN=32, BK=64; wave tile 80x16 per matrix,
// BOTH matrices per wave (acc=40). LDS 56 KB = single-buf A (swizzled) + dbuf B
// -> 2 CONCURRENT blocks/CU: co-resident block covers barrier/vmcnt drains.
// Register-disciplined: A staged in two sequential 16-reg chunks; only bR[8]
// persists across compute. Swizzle chunk c -> c^(row&7): 0 bank conflicts.
__global__ __launch_bounds__(512, 4) void gemm_swiglu(
    const u16* __restrict__ Xb,
    const float* __restrict__ wg, const float* __restrict__ wu,
    const int* __restrict__ offs, const int* __restrict__ desc,
    u16* __restrict__ Hb) {
  __shared__ u16 As[BM * 64];          // 40 KB
  __shared__ u16 Bs[2][2][32 * 64];    // 16 KB  [buf][mat][n*64 ^swz]

  const int d = desc[blockIdx.y];
  if (d < 0) return;
  const int e = d >> 12;
  const int slot0 = d & 0xFFF;
  const int Msub = offs[e + 1] - slot0;
  const int n0 = blockIdx.x * 32;

  const int t = threadIdx.x;
  const int lane = t & 63;
  const int W = t >> 6;      // 0..7
  const int wm = W >> 1;     // 4 m-strips of 80 rows
  const int wn = W & 1;      // 2 n-strips of 16 cols
  const int l15 = lane & 15;
  const int lhi = lane >> 4;

  // A staging: 640 tasks (320 rows x 2 halves of 32 elems); t -> task t; t<128 also 512+t
  const int a_row1 = t >> 1;
  const int a_h1 = (t & 1) * 4;        // chunk base (4 chunks of 8 elems)
  const u16* a_src1 = Xb + (size_t)min(slot0 + a_row1, NTOK - 1) * DDIM + a_h1 * 8;
  const int a_sz1 = a_row1 & 7;
  const int a_row2 = 256 + (t >> 1);
  const u16* a_src2 = Xb + (size_t)min(slot0 + a_row2, NTOK - 1) * DDIM + a_h1 * 8;
  const int a_sz2 = a_row2 & 7;
  const bool do_a2 = t < 128;

  // B staging: t<256 -> G(wg), else U(wu); tb -> (n = tb&31, chunk c = tb>>5)
  const int tb = t & 255;
  const int matsel = t >> 8;
  const float* b_base = (matsel ? wu : wg) + (size_t)e * DDIM * HDIM;
  const int b_n = tb & 31;
  const int b_c = tb >> 5;
  const float* b_src = b_base + (size_t)(b_c * 8) * HDIM + n0 + b_n;
  const int b_off = b_n * 64 + ((b_c ^ (b_n & 7)) << 3);

  float bR[8];
  f32x4 accg[5] = {};
  f32x4 accu[5] = {};

  // A staged as two sequential 16-reg chunks (bounded transient pressure)
  #define ASTAGE(tile) { \
    { const uint4* p_ = (const uint4*)(a_src1 + (tile) * BK); \
      uint4 v0_ = p_[0], v1_ = p_[1], v2_ = p_[2], v3_ = p_[3]; \
      u16* b_ = &As[a_row1 * 64]; \
      *(uint4*)(b_ + (((a_h1 + 0) ^ a_sz1) << 3)) = v0_; \
      *(uint4*)(b_ + (((a_h1 + 1) ^ a_sz1) << 3)) = v1_; \
      *(uint4*)(b_ + (((a_h1 + 2) ^ a_sz1) << 3)) = v2_; \
      *(uint4*)(b_ + (((a_h1 + 3) ^ a_sz1) << 3)) = v3_; } \
    if (do_a2) { const uint4* p_ = (const uint4*)(a_src2 + (tile) * BK); \
      uint4 v0_ = p_[0], v1_ = p_[1], v2_ = p_[2], v3_ = p_[3]; \
      u16* b_ = &As[a_row2 * 64]; \
      *(uint4*)(b_ + (((a_h1 + 0) ^ a_sz2) << 3)) = v0_; \
      *(uint4*)(b_ + (((a_h1 + 1) ^ a_sz2) << 3)) = v1_; \
      *(uint4*)(b_ + (((a_h1 + 2) ^ a_sz2) << 3)) = v2_; \
      *(uint4*)(b_ + (((a_h1 + 3) ^ a_sz2) << 3)) = v3_; } \
  }
  #define LOADB(tile) { const float* p_ = b_src + (size_t)(tile) * BK * HDIM; \
    _Pragma("unroll") for (int j = 0; j < 8; j++) bR[j] = p_[(size_t)j * HDIM]; }
  #define WRITEB(buf) { uint4 w_; \
    w_.x = pk2(bR[0], bR[1]); w_.y = pk2(bR[2], bR[3]); \
    w_.z = pk2(bR[4], bR[5]); w_.w = pk2(bR[6], bR[7]); \
    *(uint4*)(&Bs[buf][matsel][b_off]) = w_; }
  #define COMPUTE(buf) { _Pragma("unroll") for (int ks = 0; ks < 2; ks++) { \
      const int cx_ = (((ks << 2) + lhi) ^ (l15 & 7)) << 3; \
      bf16x8 bg_ = *(const bf16x8*)(&Bs[buf][0][(wn * 16 + l15) * 64] + cx_); \
      bf16x8 bu_ = *(const bf16x8*)(&Bs[buf][1][(wn * 16 + l15) * 64] + cx_); \
      _Pragma("unroll") for (int fm = 0; fm < 5; fm++) { \
        bf16x8 af_ = *(const bf16x8*)(&As[(wm * 80 + fm * 16 + l15) * 64] + cx_); \
        accg[fm] = __builtin_amdgcn_mfma_f32_16x16x32_bf16(af_, bg_, accg[fm], 0, 0, 0); \
        accu[fm] = __builtin_amdgcn_mfma_f32_16x16x32_bf16(af_, bu_, accu[fm], 0, 0, 0); } } }

  LOADB(0);   // bR = tile 0

  #pragma unroll 1
  for (int it = 0; it < 16; ++it) {
    const int buf = it & 1;
    if (it) __syncthreads();     // WAR on As (+ drains; co-resident block covers)
    ASTAGE(it);
    WRITEB(buf);                 // tile it from bR (arrived: loaded a full phase ago)
    if (it + 1 < 16) LOADB(it + 1);  // spans BAR + COMPUTE
    BAR();
    COMPUTE(buf);
  }
  #undef ASTAGE
  #undef LOADB
  #undef WRITEB
  #undef COMPUTE

  // epilogue: silu(g)*u -> bf16 Hb  (C/D map: col=lane&15, row=(lane>>4)*4+i)
  #pragma unroll
  for (int fm = 0; fm < 5; fm++) {
    #pragma unroll
    for (int i = 0; i < 4; i++) {
      const int row = wm * 80 + fm * 16 + lhi * 4 + i;
      if (row < Msub) {
        const float g = accg[fm][i];
        const float u = accu[fm][i];
        const float h = (g / (1.0f + __expf(-g))) * u;
        Hb[(size_t)(slot0 + row) * HDIM + n0 + wn * 16 + l15] = f2bf(h);
      }
    }
  }
}

// ---------------- pass 2: Y = (H @ wd) * wsel, split-K=4, scatter-add ----------------
// R13-verbatim (best measured). BN=128, wave tile 80x32, 256 useful blocks = 1/CU.
__global__ __launch_bounds__(1024, 4) void gemm_down(
    const u16* __restrict__ Hb, const float* __restrict__ wd,
    const int* __restrict__ offs, const int* __restrict__ desc,
    const int* __restrict__ perm, const float* __restrict__ wsel,
    float* __restrict__ y) {
  __shared__ u16 As[2][BM * 64];       // 80 KB
  __shared__ u16 Bs[2][128 * 64];      // 32 KB

  const int d = desc[blockIdx.y];
  if (d < 0) return;
  const int e = d >> 12;
  const int slot0 = d & 0xFFF;
  const int Msub = offs[e + 1] - slot0;
  const int n0 = blockIdx.x * 128;
  const int kbase = blockIdx.z * (HDIM / 4);

  const float* Wd = wd + (size_t)e * HDIM * DDIM;

  const int t = threadIdx.x;
  const int lane = t & 63;
  const int W = t >> 6;
  const int wm = W >> 2;   // 4 m-strips of 80
  const int wn = W & 3;    // 4 n-strips of 32
  const int l15 = lane & 15;
  const int lhi = lane >> 4;

  const bool do_a = t < 640;
  const int a_row = t >> 1;
  const int a_c0 = (t & 1) * 4;
  const u16* a_src = Hb + (size_t)min(slot0 + a_row, NTOK - 1) * HDIM + kbase + a_c0 * 8;
  const int a_swz = a_row & 7;

  const int b_n = t & 127;
  const int b_c = t >> 7;
  const float* b_src = Wd + (size_t)(kbase + b_c * 8) * DDIM + n0 + b_n;
  const int b_off = b_n * 64 + ((b_c ^ (b_n & 7)) << 3);

  float bR[8];
  uint4 aT0, aT1, aT2, aT3;
  f32x4 acc[5][2] = {};

  #define AISSUE(tile) if (do_a) { const uint4* p_ = (const uint4*)(a_src + (tile) * BK); \
    aT0 = p_[0]; aT1 = p_[1]; aT2 = p_[2]; aT3 = p_[3]; }
  #define AWRITE(buf) if (do_a) { u16* base_ = &As[buf][a_row * 64]; \
    *(uint4*)(base_ + (((a_c0 + 0) ^ a_swz) << 3)) = aT0; \
    *(uint4*)(base_ + (((a_c0 + 1) ^ a_swz) << 3)) = aT1; \
    *(uint4*)(base_ + (((a_c0 + 2) ^ a_swz) << 3)) = aT2; \
    *(uint4*)(base_ + (((a_c0 + 3) ^ a_swz) << 3)) = aT3; }
  #define LOADB(tile) { const float* p_ = b_src + (size_t)(tile) * BK * DDIM; \
    _Pragma("unroll") for (int j = 0; j < 8; j++) bR[j] = p_[(size_t)j * DDIM]; }
  #define WRITEB(buf) { uint4 w_; \
    w_.x = pk2(bR[0], bR[1]); w_.y = pk2(bR[2], bR[3]); \
    w_.z = pk2(bR[4], bR[5]); w_.w = pk2(bR[6], bR[7]); \
    *(uint4*)(&Bs[buf][b_off]) = w_; }
  #define COMPUTE(buf) { _Pragma("unroll") for (int ks = 0; ks < 2; ks++) { \
      const int cx_ = (((ks << 2) + lhi) ^ (l15 & 7)) << 3; \
      bf16x8 bf0_ = *(const bf16x8*)(&Bs[buf][(wn * 32 + l15) * 64] + cx_); \
      bf16x8 bf1_ = *(const bf16x8*)(&Bs[buf][(wn * 32 + 16 + l15) * 64] + cx_); \
      _Pragma("unroll") for (int fm = 0; fm < 5; fm++) { \
        bf16x8 af_ = *(const bf16x8*)(&As[buf][(wm * 80 + fm * 16 + l15) * 64] + cx_); \
        acc[fm][0] = __builtin_amdgcn_mfma_f32_16x16x32_bf16(af_, bf0_, acc[fm][0], 0, 0, 0); \
        acc[fm][1] = __builtin_amdgcn_mfma_f32_16x16x32_bf16(af_, bf1_, acc[fm][1], 0, 0, 0); } } }

  LOADB(0);
  AISSUE(0);
  WRITEB(0);
  LOADB(1);
  AWRITE(0);
  BAR();

  #pragma unroll 1
  for (int it = 0; it < 16; it += 2) {
    if (it + 1 < 16) AISSUE(it + 1);
    __builtin_amdgcn_sched_barrier(0);
    COMPUTE(0);
    if (it + 1 < 16) {
      WRITEB(1);
      if (it + 2 < 16) LOADB(it + 2);
      AWRITE(1);
    }
    BAR();
    if (it + 2 < 16) AISSUE(it + 2);
    __builtin_amdgcn_sched_barrier(0);
    COMPUTE(1);
    if (it + 2 < 16) {
      WRITEB(0);
      if (it + 3 < 16) LOADB(it + 3);
      AWRITE(0);
    }
    BAR();
  }
  #undef AISSUE
  #undef AWRITE
  #undef LOADB
  #undef WRITEB
  #undef COMPUTE

  // epilogue: scale by routing weight, scatter-add (4 K-quarters, commutative)
  #pragma unroll
  for (int fm = 0; fm < 5; fm++) {
    #pragma unroll
    for (int i = 0; i < 4; i++) {
      const int row = wm * 80 + fm * 16 + lhi * 4 + i;
      if (row < Msub) {
        const int slot = slot0 + row;
        const int tok = perm[slot];
        const float w = wsel[slot];
        const size_t base = (size_t)tok * DDIM + n0 + wn * 32;
        atomicAdd(y + base + l15, acc[fm][0][i] * w);
        atomicAdd(y + base + 16 + l15, acc[fm][1][i] * w);
      }
    }
  }
}

extern "C" void kernel_launch(void* const* d_in, const int* in_sizes, int n_in,
                              void* d_out, int out_size, void* d_ws, size_t ws_size,
                              hipStream_t stream) {
  const float* x  = (const float*)d_in[0];
  const float* cw = (const float*)d_in[1];
  const float* wg = (const float*)d_in[2];
  const float* wu = (const float*)d_in[3];
  const float* wd = (const float*)d_in[4];
  float* y = (float*)d_out;

  char* ws = (char*)d_ws;
  int* offs   = (int*)ws;                          // 16 ints
  int* desc   = (int*)(ws + 64);                   // 16 ints
  int* perm   = (int*)(ws + 128);                  // 2048 ints
  float* wsel = (float*)(ws + 128 + NTOK * 4);     // 2048 floats
  u16* Xb = (u16*)(ws + 32768);                                    // 4 MB
  u16* Hb = (u16*)(ws + 32768 + (size_t)NTOK * DDIM * 2);          // 16 MB

  hipMemsetAsync(d_out, 0, (size_t)NTOK * DDIM * sizeof(float), stream);
  route_kernel<<<1, 256, 0, stream>>>(cw, offs, perm, wsel, desc);
  gather_x<<<NTOK, 256, 0, stream>>>(x, perm, Xb);
  gemm_swiglu<<<dim3(HDIM / 32, NDESC), 512, 0, stream>>>(Xb, wg, wu, offs, desc, Hb);
  gemm_down<<<dim3(DDIM / 128, NDESC, 4), 1024, 0, stream>>>(Hb, wd, offs, desc, perm, wsel, y);
}

// Round 19
// 151.602 us; speedup vs baseline: 1.1682x; 1.1682x over previous
//
#include <hip/hip_runtime.h>
#include <hip/hip_bf16.h>

typedef __attribute__((ext_vector_type(8))) short bf16x8;
typedef __attribute__((ext_vector_type(4))) float f32x4;
typedef unsigned short u16;

#define NTOK 2048
#define DDIM 1024
#define HDIM 4096
#define KEXP 8

#define BM 320   // covers any realistic expert count in ONE tile (counts ~256±15)
#define BK 64
#define NDESC 16

__device__ __forceinline__ u16 f2bf(float f) {
  __hip_bfloat16 b = __float2bfloat16(f);   // RNE; pairs fuse to v_cvt_pk_bf16_f32
  union { __hip_bfloat16 b; u16 u; } c; c.b = b; return c.u;
}
__device__ __forceinline__ unsigned pk2(float a, float b) {
  return (unsigned)f2bf(a) | ((unsigned)f2bf(b) << 16);
}

// fenced raw barrier: own DS ops drained, no vmcnt drain, no code motion across
#define BAR() do { \
  asm volatile("s_waitcnt lgkmcnt(0)" ::: "memory"); \
  __builtin_amdgcn_sched_barrier(0); \
  __builtin_amdgcn_s_barrier(); \
  __builtin_amdgcn_sched_barrier(0); \
} while (0)

// ---------------- routing: counting sort + tile worklist ----------------
__global__ void route_kernel(const float* __restrict__ cw, int* __restrict__ offs,
                             int* __restrict__ perm, float* __restrict__ wsel,
                             int* __restrict__ desc) {
  __shared__ int cnt[KEXP];
  __shared__ int base[KEXP];
  const int t = threadIdx.x;  // 256 threads, 8 tokens each
  if (t < KEXP) cnt[t] = 0;
  __syncthreads();
  int eid[8]; float wv[8];
  #pragma unroll
  for (int i = 0; i < 8; i++) {
    const int tok = t * 8 + i;
    const float* p = cw + tok * KEXP;
    int best = 0; float bw = p[0];
    #pragma unroll
    for (int k = 1; k < KEXP; k++) { float v = p[k]; if (v > bw) { bw = v; best = k; } }
    eid[i] = best; wv[i] = bw;
    atomicAdd(&cnt[best], 1);
  }
  __syncthreads();
  if (t == 0) {
    int s = 0, nd = 0;
    for (int k = 0; k < KEXP; k++) {
      const int ck = cnt[k];
      base[k] = s; offs[k] = s;
      for (int m0 = 0; m0 < ck && nd < NDESC; m0 += BM)
        desc[nd++] = (k << 12) | (s + m0);   // pack expert(3b) | slot0(12b)
      s += ck;
    }
    offs[KEXP] = s;
    for (; nd < NDESC; nd++) desc[nd] = -1;
  }
  __syncthreads();
  #pragma unroll
  for (int i = 0; i < 8; i++) {
    const int tok = t * 8 + i;
    const int pos = atomicAdd(&base[eid[i]], 1);
    perm[pos] = tok;
    wsel[pos] = wv[i];
  }
}

// ---------------- gather x rows into expert-sorted bf16 ----------------
__global__ void gather_x(const float* __restrict__ x, const int* __restrict__ perm,
                         u16* __restrict__ Xb) {
  const int slot = blockIdx.x;
  const int tok = perm[slot];
  const int t = threadIdx.x;  // 256
  float4 v = ((const float4*)(x + (size_t)tok * DDIM))[t];
  ushort4 o; o.x = f2bf(v.x); o.y = f2bf(v.y); o.z = f2bf(v.z); o.w = f2bf(v.w);
  ((ushort4*)(Xb + (size_t)slot * DDIM))[t] = o;
}

// ---------------- pass 1: H = silu(X@wg) * (X@wu) ----------------
// R13 base (best measured) + PADDING-ROW ELIMINATION: BM=320 covers Msub~256-271,
// so ~18% of A-LDS traffic + MFMA work was clamp-padding. fm_lim (wave-uniform)
// skips dead 16-row fragments in COMPUTE (no barriers inside -> race-free);
// A staging skips rows >= ceil16(Msub) (partial fragment still staged).
// 1024 thr = 16 waves (4m x 4n), BM=320, BN=64, BK=64. Swizzled LDS, dbuf,
// compute-first phases, raw fenced barrier, no vmcnt(0) in loop.
__global__ __launch_bounds__(1024, 4) void gemm_swiglu(
    const u16* __restrict__ Xb,
    const float* __restrict__ wg, const float* __restrict__ wu,
    const int* __restrict__ offs, const int* __restrict__ desc,
    u16* __restrict__ Hb) {
  __shared__ u16 As[2][BM * 64];       // 80 KB
  __shared__ u16 Bs[2][2][64 * 64];    // 32 KB  [buf][mat][n*64 ^swz]

  const int d = desc[blockIdx.y];
  if (d < 0) return;
  const int e = d >> 12;
  const int slot0 = d & 0xFFF;
  const int Msub = offs[e + 1] - slot0;
  const int mceil = min(BM, (Msub + 15) & ~15);   // staged-row bound
  const int n0 = blockIdx.x * 64;

  const int t = threadIdx.x;
  const int lane = t & 63;
  const int W = t >> 6;
  const int wm = W >> 2;     // 4 m-strips of 80 rows
  const int wn = W & 3;      // 4 n-strips of 16 cols
  const int l15 = lane & 15;
  const int lhi = lane >> 4;
  // wave-uniform count of live 16-row fragments in this wave's 80-row strip
  const int fm_lim = min(5, max(0, (Msub - wm * 80 + 15) >> 4));

  // A staging: threads 0..639 -> row t>>1, chunks (t&1)*4 .. +3 (32 elems)
  const int a_row = t >> 1;
  const bool do_a = (t < 640) && (a_row < mceil);
  const int a_c0 = (t & 1) * 4;
  const u16* a_src = Xb + (size_t)min(slot0 + a_row, NTOK - 1) * DDIM + a_c0 * 8;
  const int a_swz = a_row & 7;

  // B staging: t<512 -> G(wg), else U(wu); thread -> (n = tb&63, chunk c = tb>>6)
  const int tb = t & 511;
  const int matsel = t >> 9;
  const float* b_base = (matsel ? wu : wg) + (size_t)e * DDIM * HDIM;
  const int b_n = tb & 63;
  const int b_c = tb >> 6;
  const float* b_src = b_base + (size_t)(b_c * 8) * HDIM + n0 + b_n;
  const int b_off = b_n * 64 + ((b_c ^ (b_n & 7)) << 3);

  float bR[8];
  uint4 aT0, aT1, aT2, aT3;            // A in-flight regs (live across COMPUTE)
  f32x4 accg[5] = {};
  f32x4 accu[5] = {};

  #define AISSUE(tile) if (do_a) { const uint4* p_ = (const uint4*)(a_src + (tile) * BK); \
    aT0 = p_[0]; aT1 = p_[1]; aT2 = p_[2]; aT3 = p_[3]; }
  #define AWRITE(buf) if (do_a) { u16* base_ = &As[buf][a_row * 64]; \
    *(uint4*)(base_ + (((a_c0 + 0) ^ a_swz) << 3)) = aT0; \
    *(uint4*)(base_ + (((a_c0 + 1) ^ a_swz) << 3)) = aT1; \
    *(uint4*)(base_ + (((a_c0 + 2) ^ a_swz) << 3)) = aT2; \
    *(uint4*)(base_ + (((a_c0 + 3) ^ a_swz) << 3)) = aT3; }
  #define LOADB(tile) { const float* p_ = b_src + (size_t)(tile) * BK * HDIM; \
    _Pragma("unroll") for (int j = 0; j < 8; j++) bR[j] = p_[(size_t)j * HDIM]; }
  #define WRITEB(buf) { uint4 w_; \
    w_.x = pk2(bR[0], bR[1]); w_.y = pk2(bR[2], bR[3]); \
    w_.z = pk2(bR[4], bR[5]); w_.w = pk2(bR[6], bR[7]); \
    *(uint4*)(&Bs[buf][matsel][b_off]) = w_; }
  #define COMPUTE(buf) { _Pragma("unroll") for (int ks = 0; ks < 2; ks++) { \
      const int cx_ = (((ks << 2) + lhi) ^ (l15 & 7)) << 3; \
      bf16x8 bg_ = *(const bf16x8*)(&Bs[buf][0][(wn * 16 + l15) * 64] + cx_); \
      bf16x8 bu_ = *(const bf16x8*)(&Bs[buf][1][(wn * 16 + l15) * 64] + cx_); \
      _Pragma("unroll") for (int fm = 0; fm < 5; fm++) { \
        if (fm < fm_lim) { \
          bf16x8 af_ = *(const bf16x8*)(&As[buf][(wm * 80 + fm * 16 + l15) * 64] + cx_); \
          accg[fm] = __builtin_amdgcn_mfma_f32_16x16x32_bf16(af_, bg_, accg[fm], 0, 0, 0); \
          accu[fm] = __builtin_amdgcn_mfma_f32_16x16x32_bf16(af_, bu_, accu[fm], 0, 0, 0); } } } }

  // prologue: stage tile0 -> buf0; leave bR = tile1
  LOADB(0);
  AISSUE(0);
  WRITEB(0);
  LOADB(1);
  AWRITE(0);
  BAR();

  #pragma unroll 1
  for (int it = 0; it < 16; it += 2) {
    // even phase: compute tile it (buf0); stage tile it+1 -> buf1
    if (it + 1 < 16) AISSUE(it + 1);
    __builtin_amdgcn_sched_barrier(0);     // keep A-issue at phase head
    COMPUTE(0);
    if (it + 1 < 16) {
      WRITEB(1);
      if (it + 2 < 16) LOADB(it + 2);
      AWRITE(1);
    }
    BAR();
    // odd phase: compute tile it+1 (buf1); stage tile it+2 -> buf0
    if (it + 2 < 16) AISSUE(it + 2);
    __builtin_amdgcn_sched_barrier(0);
    COMPUTE(1);
    if (it + 2 < 16) {
      WRITEB(0);
      if (it + 3 < 16) LOADB(it + 3);
      AWRITE(0);
    }
    BAR();
  }
  #undef AISSUE
  #undef AWRITE
  #undef LOADB
  #undef WRITEB
  #undef COMPUTE

  // epilogue: silu(g)*u -> bf16 Hb  (C/D map: col=lane&15, row=(lane>>4)*4+i)
  #pragma unroll
  for (int fm = 0; fm < 5; fm++) {
    #pragma unroll
    for (int i = 0; i < 4; i++) {
      const int row = wm * 80 + fm * 16 + lhi * 4 + i;
      if (row < Msub) {
        const float g = accg[fm][i];
        const float u = accu[fm][i];
        const float h = (g / (1.0f + __expf(-g))) * u;
        Hb[(size_t)(slot0 + row) * HDIM + n0 + wn * 16 + l15] = f2bf(h);
      }
    }
  }
}

// ---------------- pass 2: Y = (H @ wd) * wsel, split-K=4, scatter-add ----------------
// R13 base + same padding-row elimination. BN=128, wave tile 80x32, 1/CU.
__global__ __launch_bounds__(1024, 4) void gemm_down(
    const u16* __restrict__ Hb, const float* __restrict__ wd,
    const int* __restrict__ offs, const int* __restrict__ desc,
    const int* __restrict__ perm, const float* __restrict__ wsel,
    float* __restrict__ y) {
  __shared__ u16 As[2][BM * 64];       // 80 KB
  __shared__ u16 Bs[2][128 * 64];      // 32 KB

  const int d = desc[blockIdx.y];
  if (d < 0) return;
  const int e = d >> 12;
  const int slot0 = d & 0xFFF;
  const int Msub = offs[e + 1] - slot0;
  const int mceil = min(BM, (Msub + 15) & ~15);
  const int n0 = blockIdx.x * 128;
  const int kbase = blockIdx.z * (HDIM / 4);

  const float* Wd = wd + (size_t)e * HDIM * DDIM;

  const int t = threadIdx.x;
  const int lane = t & 63;
  const int W = t >> 6;
  const int wm = W >> 2;   // 4 m-strips of 80
  const int wn = W & 3;    // 4 n-strips of 32
  const int l15 = lane & 15;
  const int lhi = lane >> 4;
  const int fm_lim = min(5, max(0, (Msub - wm * 80 + 15) >> 4));

  const int a_row = t >> 1;
  const bool do_a = (t < 640) && (a_row < mceil);
  const int a_c0 = (t & 1) * 4;
  const u16* a_src = Hb + (size_t)min(slot0 + a_row, NTOK - 1) * HDIM + kbase + a_c0 * 8;
  const int a_swz = a_row & 7;

  const int b_n = t & 127;
  const int b_c = t >> 7;
  const float* b_src = Wd + (size_t)(kbase + b_c * 8) * DDIM + n0 + b_n;
  const int b_off = b_n * 64 + ((b_c ^ (b_n & 7)) << 3);

  float bR[8];
  uint4 aT0, aT1, aT2, aT3;
  f32x4 acc[5][2] = {};

  #define AISSUE(tile) if (do_a) { const uint4* p_ = (const uint4*)(a_src + (tile) * BK); \
    aT0 = p_[0]; aT1 = p_[1]; aT2 = p_[2]; aT3 = p_[3]; }
  #define AWRITE(buf) if (do_a) { u16* base_ = &As[buf][a_row * 64]; \
    *(uint4*)(base_ + (((a_c0 + 0) ^ a_swz) << 3)) = aT0; \
    *(uint4*)(base_ + (((a_c0 + 1) ^ a_swz) << 3)) = aT1; \
    *(uint4*)(base_ + (((a_c0 + 2) ^ a_swz) << 3)) = aT2; \
    *(uint4*)(base_ + (((a_c0 + 3) ^ a_swz) << 3)) = aT3; }
  #define LOADB(tile) { const float* p_ = b_src + (size_t)(tile) * BK * DDIM; \
    _Pragma("unroll") for (int j = 0; j < 8; j++) bR[j] = p_[(size_t)j * DDIM]; }
  #define WRITEB(buf) { uint4 w_; \
    w_.x = pk2(bR[0], bR[1]); w_.y = pk2(bR[2], bR[3]); \
    w_.z = pk2(bR[4], bR[5]); w_.w = pk2(bR[6], bR[7]); \
    *(uint4*)(&Bs[buf][b_off]) = w_; }
  #define COMPUTE(buf) { _Pragma("unroll") for (int ks = 0; ks < 2; ks++) { \
      const int cx_ = (((ks << 2) + lhi) ^ (l15 & 7)) << 3; \
      bf16x8 bf0_ = *(const bf16x8*)(&Bs[buf][(wn * 32 + l15) * 64] + cx_); \
      bf16x8 bf1_ = *(const bf16x8*)(&Bs[buf][(wn * 32 + 16 + l15) * 64] + cx_); \
      _Pragma("unroll") for (int fm = 0; fm < 5; fm++) { \
        if (fm < fm_lim) { \
          bf16x8 af_ = *(const bf16x8*)(&As[buf][(wm * 80 + fm * 16 + l15) * 64] + cx_); \
          acc[fm][0] = __builtin_amdgcn_mfma_f32_16x16x32_bf16(af_, bf0_, acc[fm][0], 0, 0, 0); \
          acc[fm][1] = __builtin_amdgcn_mfma_f32_16x16x32_bf16(af_, bf1_, acc[fm][1], 0, 0, 0); } } } }

  LOADB(0);
  AISSUE(0);
  WRITEB(0);
  LOADB(1);
  AWRITE(0);
  BAR();

  #pragma unroll 1
  for (int it = 0; it < 16; it += 2) {
    if (it + 1 < 16) AISSUE(it + 1);
    __builtin_amdgcn_sched_barrier(0);
    COMPUTE(0);
    if (it + 1 < 16) {
      WRITEB(1);
      if (it + 2 < 16) LOADB(it + 2);
      AWRITE(1);
    }
    BAR();
    if (it + 2 < 16) AISSUE(it + 2);
    __builtin_amdgcn_sched_barrier(0);
    COMPUTE(1);
    if (it + 2 < 16) {
      WRITEB(0);
      if (it + 3 < 16) LOADB(it + 3);
      AWRITE(0);
    }
    BAR();
  }
  #undef AISSUE
  #undef AWRITE
  #undef LOADB
  #undef WRITEB
  #undef COMPUTE

  // epilogue: scale by routing weight, scatter-add (4 K-quarters, commutative)
  #pragma unroll
  for (int fm = 0; fm < 5; fm++) {
    #pragma unroll
    for (int i = 0; i < 4; i++) {
      const int row = wm * 80 + fm * 16 + lhi * 4 + i;
      if (row < Msub) {
        const int slot = slot0 + row;
        const int tok = perm[slot];
        const float w = wsel[slot];
        const size_t base = (size_t)tok * DDIM + n0 + wn * 32;
        atomicAdd(y + base + l15, acc[fm][0][i] * w);
        atomicAdd(y + base + 16 + l15, acc[fm][1][i] * w);
      }
    }
  }
}

extern "C" void kernel_launch(void* const* d_in, const int* in_sizes, int n_in,
                              void* d_out, int out_size, void* d_ws, size_t ws_size,
                              hipStream_t stream) {
  const float* x  = (const float*)d_in[0];
  const float* cw = (const float*)d_in[1];
  const float* wg = (const float*)d_in[2];
  const float* wu = (const float*)d_in[3];
  const float* wd = (const float*)d_in[4];
  float* y = (float*)d_out;

  char* ws = (char*)d_ws;
  int* offs   = (int*)ws;                          // 16 ints
  int* desc   = (int*)(ws + 64);                   // 16 ints
  int* perm   = (int*)(ws + 128);                  // 2048 ints
  float* wsel = (float*)(ws + 128 + NTOK * 4);     // 2048 floats
  u16* Xb = (u16*)(ws + 32768);                                    // 4 MB
  u16* Hb = (u16*)(ws + 32768 + (size_t)NTOK * DDIM * 2);          // 16 MB

  hipMemsetAsync(d_out, 0, (size_t)NTOK * DDIM * sizeof(float), stream);
  route_kernel<<<1, 256, 0, stream>>>(cw, offs, perm, wsel, desc);
  gather_x<<<NTOK, 256, 0, stream>>>(x, perm, Xb);
  gemm_swiglu<<<dim3(HDIM / 64, NDESC), 1024, 0, stream>>>(Xb, wg, wu, offs, desc, Hb);
  gemm_down<<<dim3(DDIM / 128, NDESC, 4), 1024, 0, stream>>>(Hb, wd, offs, desc, perm, wsel, y);
}